// Round 11
// baseline (3634.032 us; speedup 1.0000x reference)
//
#include <hip/hip_runtime.h>

typedef unsigned short u16;
typedef __attribute__((ext_vector_type(8))) short short8;
typedef __attribute__((ext_vector_type(8))) unsigned short ushort8;
typedef __attribute__((ext_vector_type(4))) unsigned short ushort4v;
typedef __attribute__((ext_vector_type(4))) float f32x4;

#define NB 4
#define SS 4096
#define DD 1024
#define CFENCE asm volatile("" ::: "memory")

__device__ __forceinline__ u16 f2bf(float x) {
  unsigned u = __builtin_bit_cast(unsigned, x);
  u = (u + 0x7FFFu + ((u >> 16) & 1u)) >> 16;
  return (u16)u;
}
__device__ __forceinline__ float bf2f(u16 b) {
  unsigned u = ((unsigned)b) << 16;
  return __builtin_bit_cast(float, u);
}
__device__ __forceinline__ void gload16(const void* g, void* l) {
  __builtin_amdgcn_global_load_lds((const __attribute__((address_space(1))) void*)g,
                                   (__attribute__((address_space(3))) void*)l, 16, 0, 0);
}
// bijective XCD-aware swizzle (m204)
__device__ __forceinline__ int xcd_swz(int bid, int nwg) {
  const int x = bid & 7, idx = bid >> 3;
  const int q = nwg >> 3, r = nwg & 7;
  return (x < r ? x * (q + 1) : r * (q + 1) + (x - r) * q) + idx;
}

// ---------------- kernel 1: logits (f32), loss partials, pred, h->bf16 -----
__global__ __launch_bounds__(256) void k_logits(
    const float* __restrict__ h, const int* __restrict__ lab,
    const float* __restrict__ Wl, const float* __restrict__ bl,
    u16* __restrict__ h16, int* __restrict__ pred, float* __restrict__ lossPart)
{
  const int t = threadIdx.x, w = t >> 6, lane = t & 63;
  const int tok = blockIdx.x * 4 + w;
  const float4* h4p = (const float4*)(h + (size_t)tok * DD);
  const float4* wl4 = (const float4*)Wl;
  float p0 = 0.f, p1 = 0.f, p2 = 0.f, p3 = 0.f;
#pragma unroll
  for (int i = 0; i < 4; ++i) {
    const int d = i * 256 + lane * 4;
    float4 hv = h4p[i * 64 + lane];
    ushort4v hb;
    hb[0] = f2bf(hv.x); hb[1] = f2bf(hv.y); hb[2] = f2bf(hv.z); hb[3] = f2bf(hv.w);
    *(ushort4v*)(h16 + (size_t)tok * DD + d) = hb;
    float4 w0 = wl4[d], w1 = wl4[d + 1], w2 = wl4[d + 2], w3 = wl4[d + 3];
    p0 += hv.x * w0.x + hv.y * w1.x + hv.z * w2.x + hv.w * w3.x;
    p1 += hv.x * w0.y + hv.y * w1.y + hv.z * w2.y + hv.w * w3.y;
    p2 += hv.x * w0.z + hv.y * w1.z + hv.z * w2.z + hv.w * w3.z;
    p3 += hv.x * w0.w + hv.y * w1.w + hv.z * w2.w + hv.w * w3.w;
  }
#pragma unroll
  for (int m = 32; m; m >>= 1) {
    p0 += __shfl_xor(p0, m); p1 += __shfl_xor(p1, m);
    p2 += __shfl_xor(p2, m); p3 += __shfl_xor(p3, m);
  }
  __shared__ float ls[4];
  if (lane == 0) {
    float l[4] = {p0 + bl[0], p1 + bl[1], p2 + bl[2], p3 + bl[3]};
    int bi = 0; float bv = l[0];
#pragma unroll
    for (int c = 1; c < 4; ++c) if (l[c] > bv) { bv = l[c]; bi = c; }
    pred[tok] = bi;
    float se = 0.f;
#pragma unroll
    for (int c = 0; c < 4; ++c) se += expf(l[c] - bv);
    float lse = bv + logf(se);
    ls[w] = lse - l[lab[tok]];
  }
  __syncthreads();
  if (t == 0) lossPart[blockIdx.x] = ls[0] + ls[1] + ls[2] + ls[3];
}

// ---------------- kernel 2: weights -> bf16. slots: 0=Wq^T 1=Wk^T 2=Wv(plain) 3=Wo^T
__global__ __launch_bounds__(256) void k_wconv(
    const float* __restrict__ W0, const float* __restrict__ W1,
    const float* __restrict__ W2, const float* __restrict__ W3,
    u16* __restrict__ Wt)
{
  const int gid = blockIdx.x * 256 + threadIdx.x;
  const int mat = gid >> 20;
  const int rem = gid & ((1 << 20) - 1);
  const int n = rem >> 10, k = rem & 1023;
  const float* W = (mat == 0) ? W0 : (mat == 1) ? W1 : (mat == 2) ? W2 : W3;
  const float v = (mat == 2) ? W[(size_t)n * 1024 + k] : W[(size_t)k * 1024 + n];
  Wt[(size_t)gid] = f2bf(v);
}

// ---------------- kernel 3: BIOS chunk scan (1 block / batch) --------------
__global__ __launch_bounds__(256) void k_scan(
    const int* __restrict__ pred, int* __restrict__ cstart, int* __restrict__ ccnt)
{
  const int b = blockIdx.x, t = threadIdx.x;
  const int4* p4 = (const int4*)(pred + (size_t)b * SS);
  int labv[16];
#pragma unroll
  for (int i = 0; i < 4; ++i) {
    int4 v = p4[t * 4 + i];
    labv[i * 4 + 0] = v.x; labv[i * 4 + 1] = v.y;
    labv[i * 4 + 2] = v.z; labv[i * 4 + 3] = v.w;
  }
  int A = 0, Bc = 1;
#pragma unroll
  for (int e = 0; e < 16; ++e) {
    int a = (labv[e] == 0), bb = (labv[e] == 1);
    A = a | (bb & A);
    Bc = bb & Bc;
  }
  __shared__ int sA[256], sB[256], sC[256];
  sA[t] = A; sB[t] = Bc;
  __syncthreads();
  for (int off = 1; off < 256; off <<= 1) {
    int pa = 0, pb = 1;
    if (t >= off) { pa = sA[t - off]; pb = sB[t - off]; }
    __syncthreads();
    A = A | (Bc & pa); Bc = Bc & pb;
    sA[t] = A; sB[t] = Bc;
    __syncthreads();
  }
  const int extIn = (t == 0) ? 0 : sA[t - 1];
  int ext = extIn, nst = 0;
#pragma unroll
  for (int e = 0; e < 16; ++e) {
    int cont = (labv[e] == 1) & ext;
    nst += !cont;
    ext = (labv[e] == 0) | cont;
  }
  sC[t] = nst;
  __syncthreads();
  int tot = nst;
  for (int off = 1; off < 256; off <<= 1) {
    int pc = 0;
    if (t >= off) pc = sC[t - off];
    __syncthreads();
    tot += pc;
    sC[t] = tot;
    __syncthreads();
  }
  const int base = tot - nst;
  const int total = sC[255];
  if (t == 0) { ccnt[b] = total; cstart[b * (SS + 1) + total] = SS; }
  ext = extIn; int id = base;
#pragma unroll
  for (int e = 0; e < 16; ++e) {
    int cont = (labv[e] == 1) & ext;
    if (!cont) cstart[b * (SS + 1) + id++] = t * 16 + e;
    ext = (labv[e] == 0) | cont;
  }
}

// ---------------- kernel 4: segment-mean pooling from h16 (1 wave / chunk) --
__global__ __launch_bounds__(256) void k_pool(
    const u16* __restrict__ h16, const int* __restrict__ cstart,
    const int* __restrict__ ccnt, u16* __restrict__ cemb)
{
  const int t = threadIdx.x, w = t >> 6, lane = t & 63;
  const int gw = blockIdx.x * 4 + w;
  const int b = gw >> 12, c = gw & (SS - 1);
  u16* out = cemb + (size_t)gw * DD + lane * 16;
  if (c >= ccnt[b]) {
    ushort8 z = {0, 0, 0, 0, 0, 0, 0, 0};
    *(ushort8*)out = z; *(ushort8*)(out + 8) = z;
    return;
  }
  const int s0 = cstart[b * (SS + 1) + c], s1 = cstart[b * (SS + 1) + c + 1];
  float acc[16] = {};
  for (int s = s0; s < s1; ++s) {
    const ushort8* hp = (const ushort8*)(h16 + ((size_t)b * SS + s) * DD + lane * 16);
    ushort8 a = hp[0], bb = hp[1];
#pragma unroll
    for (int e = 0; e < 8; ++e) { acc[e] += bf2f(a[e]); acc[8 + e] += bf2f(bb[e]); }
  }
  const float inv = 1.f / (float)(s1 - s0);
  ushort8 o0, o1;
#pragma unroll
  for (int e = 0; e < 8; ++e) { o0[e] = f2bf(acc[e] * inv); o1[e] = f2bf(acc[8 + e] * inv); }
  *(ushort8*)out = o0; *(ushort8*)(out + 8) = o1;
}

// ---------------- bvWo[n] = sum_j bv[j]*Wo[j,n] ------------------------------
__global__ __launch_bounds__(256) void k_bvwo(
    const float* __restrict__ bv, const float* __restrict__ Wo,
    const float* __restrict__ bo, float* __restrict__ outv)
{
  const int n = blockIdx.x * 256 + threadIdx.x;
  float s = 0.f;
#pragma unroll 8
  for (int j = 0; j < 1024; ++j) s += bv[j] * Wo[(size_t)j * 1024 + n];
  outv[n] = s;
}

// ---------------- Wvo^T = small 1024^3 GEMM: C[n,k]=sum_j WoT[n,j]*Wv[k,j] --
__global__ __launch_bounds__(256) void k_wvo(
    const u16* __restrict__ WoT, const u16* __restrict__ Wvn, u16* __restrict__ WvoT)
{
  __shared__ u16 lA[64 * 64], lB[64 * 64];
  const int t = threadIdx.x, lane = t & 63, w = t >> 6;
  const int m0 = blockIdx.y * 64, n0 = blockIdx.x * 64;
  const int trow = t >> 3;
  const int schunk = ((t & 7) ^ (trow & 7)) * 8;
  const u16* Ag = WoT + (size_t)(m0 + trow) * 1024 + schunk;
  const u16* Bg = Wvn + (size_t)(n0 + trow) * 1024 + schunk;
  u16* dA = lA + t * 8;
  u16* dB = lB + t * 8;
  f32x4 acc[4];
#pragma unroll
  for (int i = 0; i < 4; ++i) acc[i] = (f32x4){0.f, 0.f, 0.f, 0.f};
  const int lrow = lane & 15, hi = lane >> 4;
  const int co0 = (hi ^ (lrow & 7)) * 8;
  const int co1 = ((4 + hi) ^ (lrow & 7)) * 8;
  for (int kt = 0; kt < 1024; kt += 64) {
    gload16(Ag + kt, dA); gload16(Ag + (size_t)32 * 1024 + kt, dA + 2048);
    gload16(Bg + kt, dB); gload16(Bg + (size_t)32 * 1024 + kt, dB + 2048);
    __syncthreads();
#pragma unroll
    for (int ks = 0; ks < 2; ++ks) {
      const int co = ks ? co1 : co0;
      short8 af = *(const short8*)(lA + (w * 16 + lrow) * 64 + co);
#pragma unroll
      for (int ni = 0; ni < 4; ++ni) {
        short8 bf8 = *(const short8*)(lB + (ni * 16 + lrow) * 64 + co);
        acc[ni] = __builtin_amdgcn_mfma_f32_16x16x32_bf16(af, bf8, acc[ni], 0, 0, 0);
      }
    }
    __syncthreads();
  }
#pragma unroll
  for (int ni = 0; ni < 4; ++ni)
#pragma unroll
    for (int q = 0; q < 4; ++q)
      WvoT[(size_t)(m0 + w * 16 + hi * 4 + q) * 1024 + n0 + ni * 16 + lrow] = f2bf(acc[ni][q]);
}

// ---------------- 256x256 NT bf16 GEMM, BK=32, 8 waves, 64 KB LDS -----------
// 2 blocks/CU (the r10 kernel at 128 KB ran 1 block/CU; barrier bubbles had
// no other block to fill them -> 35% MfmaUtil plateau). Same r7 2-phase
// ledger, rescaled: 4 loads/tile (Ah0, Ah1, B0, B1), gate vmcnt(3).
// A load-halves are ROW-PERMUTED so Ah0 = all mh0 rows {0-63,128-191},
// Ah1 = all mh1 rows {64-127,192-255}: lds row lr=t>>2 -> phys row
// (lr&63) + ((lr>>6)<<7) + H*64. Swizzle: slot = chunk ^ ((row>>1)&3)
// (involution); read co = (hi ^ ((lrow>>1)&3))*8. Bank check: byte =
// R*64 + slot*16; bank group = (R&1)*16 + slot*4; 8 lanes/4-bank group =
// LDS floor (no conflict).
template <int OUTF32, int CLAMPK, int SKIPN, int CLAMPM>
__global__ __launch_bounds__(512, 4) void gemm256(
    const u16* __restrict__ A0p, const u16* __restrict__ A1p,
    const u16* __restrict__ A2p, const u16* __restrict__ A3p,
    const u16* __restrict__ Bt, long strideB,
    void* __restrict__ C0, void* __restrict__ C1,
    void* __restrict__ C2, void* __restrict__ C3,
    const float* __restrict__ bias, float scale, int M, int N, int K,
    const int* __restrict__ ccnt)
{
  __shared__ u16 lds[32768];  // 64 KB: A dbuf (16K u16) | B dbuf (16K u16)
  u16* ldsA = lds;
  u16* ldsB = lds + 16384;
  const int t = threadIdx.x, lane = t & 63, w = t >> 6;
  const int wr = w >> 2, wc = w & 3;
  const int z = blockIdx.z;
  const int bid = blockIdx.y * gridDim.x + blockIdx.x;
  const int swz = xcd_swz(bid, gridDim.x * gridDim.y);
  const int m0 = (swz / gridDim.x) * 256, n0 = (swz % gridDim.x) * 256;

  int NT = K >> 5;
  if (SKIPN || CLAMPK) {
    const int cb = ccnt[z];
    if (SKIPN && n0 >= ((((cb + 63) >> 6)) << 6)) return;
    if (CLAMPK) { const int ntc = (cb + 31) >> 5; if (ntc < NT) NT = ntc; }
  }
  if (CLAMPM) {
    const int bb = m0 >> 12;
    const int ntc64 = ((ccnt[bb] + 63) >> 6) << 6;
    if ((m0 & 4095) >= ntc64) return;
  }

  const u16* A = (z == 0) ? A0p : (z == 1) ? A1p : (z == 2) ? A2p : A3p;
  void* Cp    = (z == 0) ? C0 : (z == 1) ? C1 : (z == 2) ? C2 : C3;
  const u16* B = Bt + (size_t)z * strideB;

  f32x4 acc[8][4];
#pragma unroll
  for (int i = 0; i < 8; ++i)
#pragma unroll
    for (int j = 0; j < 4; ++j) acc[i][j] = (f32x4){0.f, 0.f, 0.f, 0.f};

  const int lr = t >> 2;
  const int schunk = ((t & 3) ^ ((t >> 3) & 3)) * 8;
  const int abaseRow = (lr & 63) + ((lr >> 6) << 7);   // phys row for H=0
  const u16* AgBase = A + (size_t)(m0 + abaseRow) * K + schunk;
  const u16* BgBase = B + (size_t)(n0 + lr) * K + schunk;

  // stage: 1 load per A-half, 2 for B; linear LDS dest (rule 21)
#define STG_A(BUF, H, KT) gload16(AgBase + (size_t)(H) * 64 * K + (KT), \
                                  ldsA + (BUF) * 8192 + (H) * 4096 + t * 8)
#define STG_B(BUF, KT)   { gload16(BgBase + (KT),                    ldsB + (BUF) * 8192 + t * 8); \
                           gload16(BgBase + (size_t)128 * K + (KT),  ldsB + (BUF) * 8192 + 4096 + t * 8); }
#define RD_A(MH, BUFP) \
  { _Pragma("unroll") for (int mi = 0; mi < 4; ++mi) \
      af[mi] = *(const short8*)((BUFP) + (MH) * 4096 + (wr * 64 + mi * 16 + lrow) * 32 + co); }
#define RD_B(BUFP) \
  { _Pragma("unroll") for (int ni = 0; ni < 4; ++ni) \
      bf[ni] = *(const short8*)((BUFP) + (wc * 64 + ni * 16 + lrow) * 32 + co); }
#define MFMA16(MH) \
  { _Pragma("unroll") for (int mi = 0; mi < 4; ++mi) \
      _Pragma("unroll") for (int ni = 0; ni < 4; ++ni) \
        acc[(MH) * 4 + mi][ni] = __builtin_amdgcn_mfma_f32_16x16x32_bf16( \
            af[mi], bf[ni], acc[(MH) * 4 + mi][ni], 0, 0, 0); }
// one K-tile (K=32), 2 phases. Ledger:
//  P0: RD_A(mh0)+RD_B; stage Ah1(j+1)->buf^1 [last read P1(j-1), barriered]
//  P1: RD_A(mh1); stage Ah0(j+2)+B(j+2)->buf [last read P0(j), barriered]
//  gate end-P1: vmcnt(3) -> tile j+1 (Ah0,B from P1(j-1) + Ah1 from P0(j))
//  fully landed; only P1(j)'s 3 stay in flight. j==NT-2: vmcnt(0).
#define KSTEP(BUF, JV) { \
    const u16* bufA = ldsA + (BUF) * 8192; \
    const u16* bufB = ldsB + (BUF) * 8192; \
    RD_A(0, bufA); \
    RD_B(bufB); \
    if ((JV) + 1 < NT) STG_A((BUF) ^ 1, 1, ((JV) + 1) << 5); \
    CFENCE; \
    __builtin_amdgcn_s_barrier(); \
    __builtin_amdgcn_s_setprio(1); \
    MFMA16(0); \
    __builtin_amdgcn_s_setprio(0); \
    __builtin_amdgcn_sched_barrier(0); \
    __builtin_amdgcn_s_barrier(); \
    CFENCE; \
    RD_A(1, bufA); \
    if ((JV) + 2 < NT) { STG_A((BUF), 0, ((JV) + 2) << 5); STG_B((BUF), ((JV) + 2) << 5); } \
    CFENCE; \
    __builtin_amdgcn_s_barrier(); \
    __builtin_amdgcn_s_setprio(1); \
    MFMA16(1); \
    __builtin_amdgcn_s_setprio(0); \
    if ((JV) + 2 < NT)       asm volatile("s_waitcnt vmcnt(3)" ::: "memory"); \
    else if ((JV) + 2 == NT) asm volatile("s_waitcnt vmcnt(0)" ::: "memory"); \
    __builtin_amdgcn_sched_barrier(0); \
    __builtin_amdgcn_s_barrier(); \
    CFENCE; }

  const int lrow = lane & 15, hi = lane >> 4;
  const int co = (hi ^ ((lrow >> 1) & 3)) * 8;

  // prologue: tile0 full (4 loads), tile1 Ah0+B (3); Ah1(tile1) at iter0-P0.
  STG_A(0, 0, 0); STG_A(0, 1, 0); STG_B(0, 0);
  if (NT > 1) {
    STG_A(1, 0, 32); STG_B(1, 32);
    asm volatile("s_waitcnt vmcnt(3)" ::: "memory");  // tile0's 4 landed
  } else {
    asm volatile("s_waitcnt vmcnt(0)" ::: "memory");
  }
  __builtin_amdgcn_s_barrier();
  CFENCE;

  short8 af[4], bf[4];
  int j = 0;
  for (; j + 2 <= NT; j += 2) { KSTEP(0, j); KSTEP(1, j + 1); }
  if (j < NT) KSTEP(0, j);  // odd-NT tail (j even -> buffer 0)

  // epilogue. frag (m,n): row_local = wr*128 + m*16 + (lane>>4)*4 + q,
  // col_local = wc*64 + n*16 + (lane&15)
  if (OUTF32) {
    const int rowb = m0 + wr * 128 + (lane >> 4) * 4;
#pragma unroll
    for (int n = 0; n < 4; ++n) {
      const int col = n0 + wc * 64 + n * 16 + (lane & 15);
      const float bv = bias ? bias[col] : 0.f;
#pragma unroll
      for (int m = 0; m < 8; ++m)
#pragma unroll
        for (int q = 0; q < 4; ++q)
          ((float*)Cp)[(size_t)(rowb + m * 16 + q) * N + col] = acc[m][n][q] * scale + bv;
    }
  } else {
    // 64 KB LDS holds half the C tile: do rows 0-127 (wr=0) then 128-255.
    u16* cls = lds;
    u16* Cu = (u16*)Cp;
#pragma unroll
    for (int half = 0; half < 2; ++half) {
      __syncthreads();
      if (wr == half) {
#pragma unroll
        for (int n = 0; n < 4; ++n) {
          const int coll = wc * 64 + n * 16 + (lane & 15);
          const float bv = bias ? bias[n0 + coll] : 0.f;
#pragma unroll
          for (int m = 0; m < 8; ++m)
#pragma unroll
            for (int q = 0; q < 4; ++q)
              cls[(m * 16 + (lane >> 4) * 4 + q) * 256 + coll] = f2bf(acc[m][n][q] * scale + bv);
        }
      }
      __syncthreads();
#pragma unroll
      for (int ps = 0; ps < 8; ++ps) {
        const int f = ps * 512 + t;
        const int row = f >> 5, col8 = (f & 31) * 8;
        *(ushort8*)(Cu + (size_t)(m0 + half * 128 + row) * N + n0 + col8) =
            *(const ushort8*)(cls + row * 256 + col8);
      }
    }
  }
#undef STG_A
#undef STG_B
#undef RD_A
#undef RD_B
#undef MFMA16
#undef KSTEP
}

// ---------------- masked row softmax, bf16 in-place, z-folded, col-clamped --
__global__ __launch_bounds__(256) void k_softmax(
    u16* __restrict__ s0, u16* __restrict__ s1, u16* __restrict__ s2,
    u16* __restrict__ s3, const int* __restrict__ ccnt)
{
  const int t = threadIdx.x, lane = t & 63, w = t >> 6;
  const int row = blockIdx.x, b = blockIdx.y;
  u16* sc = ((b == 0) ? s0 : (b == 1) ? s1 : (b == 2) ? s2 : s3) + (size_t)row * SS;
  const int Cb = ccnt[b];
  const int ntc64 = ((Cb + 63) >> 6) << 6;   // cols >= ntc64 never read by PV
  const int cb0 = t * 16;
  const int active = cb0 < ntc64;
  u16* p = sc + cb0;
  ushort8 v0 = {0, 0, 0, 0, 0, 0, 0, 0}, v1 = {0, 0, 0, 0, 0, 0, 0, 0};
  if (active) { v0 = *(ushort8*)p; v1 = *(ushort8*)(p + 8); }
  float x[16];
#pragma unroll
  for (int e = 0; e < 8; ++e) { x[e] = bf2f(v0[e]); x[8 + e] = bf2f(v1[e]); }
  float m = -1e30f;
#pragma unroll
  for (int e = 0; e < 16; ++e) if (cb0 + e < Cb) m = fmaxf(m, x[e]);
#pragma unroll
  for (int off = 32; off; off >>= 1) m = fmaxf(m, __shfl_xor(m, off));
  __shared__ float red[4], red2[4];
  if (lane == 0) red[w] = m;
  __syncthreads();
  m = fmaxf(fmaxf(red[0], red[1]), fmaxf(red[2], red[3]));
  float ssum = 0.f;
#pragma unroll
  for (int e = 0; e < 16; ++e) {
    float ev = (cb0 + e < Cb) ? __expf(x[e] - m) : 0.f;
    x[e] = ev; ssum += ev;
  }
#pragma unroll
  for (int off = 32; off; off >>= 1) ssum += __shfl_xor(ssum, off);
  if (lane == 0) red2[w] = ssum;
  __syncthreads();
  ssum = red2[0] + red2[1] + red2[2] + red2[3];
  const float inv = 1.f / ssum;
  if (active) {
#pragma unroll
    for (int e = 0; e < 8; ++e) { v0[e] = f2bf(x[e] * inv); v1[e] = f2bf(x[8 + e] * inv); }
    *(ushort8*)p = v0; *(ushort8*)(p + 8) = v1;
  }
}

// ---------------- bf16 transpose v[b][c][d] -> vT[b][d][c], c-clamped -------
__global__ __launch_bounds__(256) void k_transpose(
    const u16* __restrict__ v, u16* __restrict__ vt, const int* __restrict__ ccnt)
{
  const int b = blockIdx.z;
  const int c0 = blockIdx.y * 64;
  if (c0 >= (((ccnt[b] + 63) >> 6) << 6)) return;  // vt cols never read by PV
  __shared__ u16 ts[64][80];
  const int t = threadIdx.x;
  const int d0 = blockIdx.x * 64;
#pragma unroll
  for (int p = 0; p < 2; ++p) {
    const int idx = p * 256 + t, r = idx >> 3, cc = idx & 7;
    ushort8 val = *(const ushort8*)(v + ((size_t)b * SS + c0 + r) * DD + d0 + cc * 8);
    *(ushort8*)&ts[r][(cc ^ ((r >> 3) & 7)) * 8] = val;
  }
  __syncthreads();
#pragma unroll
  for (int p = 0; p < 2; ++p) {
    const int idx = p * 256 + t, r = idx >> 3, cc = idx & 7;
    ushort8 o;
#pragma unroll
    for (int e = 0; e < 8; ++e)
      o[e] = ts[cc * 8 + e][(((r >> 3) ^ cc) << 3) + (r & 7)];
    *(ushort8*)(vt + ((size_t)b * DD + d0 + r) * SS + c0 + cc * 8) = o;
  }
}

// ---------------- loss finalize ---------------------------------------------
__global__ __launch_bounds__(256) void k_lossfin(
    const float* __restrict__ part, float* __restrict__ out)
{
  const int t = threadIdx.x, lane = t & 63, w = t >> 6;
  float s = 0.f;
  for (int i = t; i < 4096; i += 256) s += part[i];
#pragma unroll
  for (int off = 32; off; off >>= 1) s += __shfl_xor(s, off);
  __shared__ float r[4];
  if (lane == 0) r[w] = s;
  __syncthreads();
  if (t == 0) out[0] = (r[0] + r[1] + r[2] + r[3]) * (1.f / (NB * SS));
}

extern "C" void kernel_launch(void* const* d_in, const int* in_sizes, int n_in,
                              void* d_out, int out_size, void* d_ws, size_t ws_size,
                              hipStream_t stream) {
  const float* h  = (const float*)d_in[0];
  const int* plab = (const int*)d_in[1];
  const float* Wl = (const float*)d_in[2];
  const float* bl = (const float*)d_in[3];
  const float* Wq = (const float*)d_in[4];
  const float* bq = (const float*)d_in[5];
  const float* Wk = (const float*)d_in[6];
  const float* bk = (const float*)d_in[7];
  const float* Wv = (const float*)d_in[8];
  const float* bv = (const float*)d_in[9];
  const float* Wo = (const float*)d_in[10];
  const float* bo = (const float*)d_in[11];
  float* out = (float*)d_out;

  char* ws = (char*)d_ws;
  const size_t SZ = (size_t)NB * SS * DD * 2;  // 32 MB
  const size_t SD = (size_t)SS * DD;           // per-batch elems
  u16* h16      = (u16*)(ws + 0 * SZ);  // dead after q-GEMM -> s0
  u16* cemb     = (u16*)(ws + 1 * SZ);  // dead after k/v2-GEMM -> s1
  u16* q        = (u16*)(ws + 2 * SZ);
  u16* kk       = (u16*)(ws + 3 * SZ);
  u16* vv       = (u16*)(ws + 4 * SZ);  // dead after transpose -> s2
  u16* vt       = (u16*)(ws + 5 * SZ);
  u16* Wt       = (u16*)(ws + 6 * SZ);  // 8 MB: Wq^T | Wk^T | Wv | Wo^T; slot0 -> Wvo^T
  char* ws2     = ws + 6 * SZ + (size_t)4 * 1024 * 1024 * 2;
  int* pred     = (int*)ws2;
  int* cstart   = (int*)(ws2 + 65536);
  int* ccnt     = (int*)(ws2 + 65536 + 4 * (SS + 1) * 4);
  float* lossPart = (float*)(ws2 + 65536 + 4 * (SS + 1) * 4 + 64);
  float* bvwo   = (float*)(ws2 + 65536 + 4 * (SS + 1) * 4 + 64 + 16384);
  // s3: fresh 32 MB at the end of ws (total footprint ~233 MB)
  u16* s3 = (u16*)(ws + 6 * SZ + (size_t)9 * 1024 * 1024);
  u16* s0 = h16;
  u16* s1 = cemb;
  u16* s2 = vv;

  k_logits<<<dim3(NB * SS / 4), 256, 0, stream>>>(h, plab, Wl, bl, h16, pred, lossPart);
  k_wconv<<<dim3(4 * 1024 * 1024 / 256), 256, 0, stream>>>(Wq, Wk, Wv, Wo, Wt);
  k_scan<<<dim3(NB), 256, 0, stream>>>(pred, cstart, ccnt);
  k_pool<<<dim3(NB * SS / 4), 256, 0, stream>>>(h16, cstart, ccnt, cemb);
  k_bvwo<<<dim3(4), 256, 0, stream>>>(bv, Wo, bo, bvwo);

  // q = h16 @ Wq + bq
  gemm256<0, 0, 0, 0><<<dim3(DD / 256, NB * SS / 256, 1), 512, 0, stream>>>(
      h16, h16, h16, h16, Wt, 0, q, q, q, q,
      bq, 1.f, NB * SS, DD, DD, nullptr);
  // Wvo^T = (Wv@Wo)^T into Wt slot0 (Wq^T dead)
  k_wvo<<<dim3(16, 16), 256, 0, stream>>>(Wt + 3 * (1 << 20), Wt + 2 * (1 << 20), Wt);
  // k = cemb @ Wk + bk  (rows >= ntc64 skipped)
  gemm256<0, 0, 0, 1><<<dim3(DD / 256, NB * SS / 256, 1), 512, 0, stream>>>(
      cemb, cemb, cemb, cemb, Wt + (1 << 20), 0, kk, kk, kk, kk,
      bk, 1.f, NB * SS, DD, DD, ccnt);
  // v2 = cemb @ Wvo + bvWo  (rows >= ntc64 skipped)
  gemm256<0, 0, 0, 1><<<dim3(DD / 256, NB * SS / 256, 1), 512, 0, stream>>>(
      cemb, cemb, cemb, cemb, Wt, 0, vv, vv, vv, vv,
      bvwo, 1.f, NB * SS, DD, DD, ccnt);
  k_transpose<<<dim3(DD / 64, SS / 64, NB), 256, 0, stream>>>(vv, vt, ccnt);

  const float scl = 1.f / 32.f;  // 1/sqrt(DC)
  // scores: all 4 batches, one dispatch
  gemm256<0, 0, 1, 0><<<dim3(SS / 256, SS / 256, NB), 512, 0, stream>>>(
      q, q + SD, q + 2 * SD, q + 3 * SD, kk, (long)SD,
      s0, s1, s2, s3, nullptr, scl, SS, SS, DD, ccnt);
  k_softmax<<<dim3(SS, NB), 256, 0, stream>>>(s0, s1, s2, s3, ccnt);
  // ch_out = attn @ v2 + bo  (K clamped to ceil(ccnt/32))
  gemm256<1, 1, 0, 0><<<dim3(DD / 256, SS / 256, NB), 512, 0, stream>>>(
      s0, s1, s2, s3, vt, (long)SD,
      out, out + SD, out + 2 * SD, out + 3 * SD,
      bo, 1.f, SS, DD, SS, ccnt);
  k_lossfin<<<dim3(1), 256, 0, stream>>>(lossPart, out + (size_t)NB * SS * DD);
}

// Round 12
// 539.876 us; speedup vs baseline: 6.7312x; 6.7312x over previous
//
#include <hip/hip_runtime.h>

typedef unsigned short u16;
typedef __attribute__((ext_vector_type(8))) short short8;
typedef __attribute__((ext_vector_type(8))) unsigned short ushort8;
typedef __attribute__((ext_vector_type(4))) unsigned short ushort4v;
typedef __attribute__((ext_vector_type(4))) float f32x4;

#define NB 4
#define SS 4096
#define DD 1024
#define CFENCE asm volatile("" ::: "memory")

__device__ __forceinline__ u16 f2bf(float x) {
  unsigned u = __builtin_bit_cast(unsigned, x);
  u = (u + 0x7FFFu + ((u >> 16) & 1u)) >> 16;
  return (u16)u;
}
__device__ __forceinline__ float bf2f(u16 b) {
  unsigned u = ((unsigned)b) << 16;
  return __builtin_bit_cast(float, u);
}
__device__ __forceinline__ void gload16(const void* g, void* l) {
  __builtin_amdgcn_global_load_lds((const __attribute__((address_space(1))) void*)g,
                                   (__attribute__((address_space(3))) void*)l, 16, 0, 0);
}
// bijective XCD-aware swizzle (m204)
__device__ __forceinline__ int xcd_swz(int bid, int nwg) {
  const int x = bid & 7, idx = bid >> 3;
  const int q = nwg >> 3, r = nwg & 7;
  return (x < r ? x * (q + 1) : r * (q + 1) + (x - r) * q) + idx;
}

// ---------------- kernel 1: logits (f32), loss partials, pred, h->bf16 -----
__global__ __launch_bounds__(256) void k_logits(
    const float* __restrict__ h, const int* __restrict__ lab,
    const float* __restrict__ Wl, const float* __restrict__ bl,
    u16* __restrict__ h16, int* __restrict__ pred, float* __restrict__ lossPart)
{
  const int t = threadIdx.x, w = t >> 6, lane = t & 63;
  const int tok = blockIdx.x * 4 + w;
  const float4* h4p = (const float4*)(h + (size_t)tok * DD);
  const float4* wl4 = (const float4*)Wl;
  float p0 = 0.f, p1 = 0.f, p2 = 0.f, p3 = 0.f;
#pragma unroll
  for (int i = 0; i < 4; ++i) {
    const int d = i * 256 + lane * 4;
    float4 hv = h4p[i * 64 + lane];
    ushort4v hb;
    hb[0] = f2bf(hv.x); hb[1] = f2bf(hv.y); hb[2] = f2bf(hv.z); hb[3] = f2bf(hv.w);
    *(ushort4v*)(h16 + (size_t)tok * DD + d) = hb;
    float4 w0 = wl4[d], w1 = wl4[d + 1], w2 = wl4[d + 2], w3 = wl4[d + 3];
    p0 += hv.x * w0.x + hv.y * w1.x + hv.z * w2.x + hv.w * w3.x;
    p1 += hv.x * w0.y + hv.y * w1.y + hv.z * w2.y + hv.w * w3.y;
    p2 += hv.x * w0.z + hv.y * w1.z + hv.z * w2.z + hv.w * w3.z;
    p3 += hv.x * w0.w + hv.y * w1.w + hv.z * w2.w + hv.w * w3.w;
  }
#pragma unroll
  for (int m = 32; m; m >>= 1) {
    p0 += __shfl_xor(p0, m); p1 += __shfl_xor(p1, m);
    p2 += __shfl_xor(p2, m); p3 += __shfl_xor(p3, m);
  }
  __shared__ float ls[4];
  if (lane == 0) {
    float l[4] = {p0 + bl[0], p1 + bl[1], p2 + bl[2], p3 + bl[3]};
    int bi = 0; float bv = l[0];
#pragma unroll
    for (int c = 1; c < 4; ++c) if (l[c] > bv) { bv = l[c]; bi = c; }
    pred[tok] = bi;
    float se = 0.f;
#pragma unroll
    for (int c = 0; c < 4; ++c) se += expf(l[c] - bv);
    float lse = bv + logf(se);
    ls[w] = lse - l[lab[tok]];
  }
  __syncthreads();
  if (t == 0) lossPart[blockIdx.x] = ls[0] + ls[1] + ls[2] + ls[3];
}

// ---------------- kernel 2: weights -> bf16. slots: 0=Wq^T 1=Wk^T 2=Wv(plain) 3=Wo^T
__global__ __launch_bounds__(256) void k_wconv(
    const float* __restrict__ W0, const float* __restrict__ W1,
    const float* __restrict__ W2, const float* __restrict__ W3,
    u16* __restrict__ Wt)
{
  const int gid = blockIdx.x * 256 + threadIdx.x;
  const int mat = gid >> 20;
  const int rem = gid & ((1 << 20) - 1);
  const int n = rem >> 10, k = rem & 1023;
  const float* W = (mat == 0) ? W0 : (mat == 1) ? W1 : (mat == 2) ? W2 : W3;
  const float v = (mat == 2) ? W[(size_t)n * 1024 + k] : W[(size_t)k * 1024 + n];
  Wt[(size_t)gid] = f2bf(v);
}

// ---------------- kernel 3: BIOS chunk scan (1 block / batch) --------------
__global__ __launch_bounds__(256) void k_scan(
    const int* __restrict__ pred, int* __restrict__ cstart, int* __restrict__ ccnt)
{
  const int b = blockIdx.x, t = threadIdx.x;
  const int4* p4 = (const int4*)(pred + (size_t)b * SS);
  int labv[16];
#pragma unroll
  for (int i = 0; i < 4; ++i) {
    int4 v = p4[t * 4 + i];
    labv[i * 4 + 0] = v.x; labv[i * 4 + 1] = v.y;
    labv[i * 4 + 2] = v.z; labv[i * 4 + 3] = v.w;
  }
  int A = 0, Bc = 1;
#pragma unroll
  for (int e = 0; e < 16; ++e) {
    int a = (labv[e] == 0), bb = (labv[e] == 1);
    A = a | (bb & A);
    Bc = bb & Bc;
  }
  __shared__ int sA[256], sB[256], sC[256];
  sA[t] = A; sB[t] = Bc;
  __syncthreads();
  for (int off = 1; off < 256; off <<= 1) {
    int pa = 0, pb = 1;
    if (t >= off) { pa = sA[t - off]; pb = sB[t - off]; }
    __syncthreads();
    A = A | (Bc & pa); Bc = Bc & pb;
    sA[t] = A; sB[t] = Bc;
    __syncthreads();
  }
  const int extIn = (t == 0) ? 0 : sA[t - 1];
  int ext = extIn, nst = 0;
#pragma unroll
  for (int e = 0; e < 16; ++e) {
    int cont = (labv[e] == 1) & ext;
    nst += !cont;
    ext = (labv[e] == 0) | cont;
  }
  sC[t] = nst;
  __syncthreads();
  int tot = nst;
  for (int off = 1; off < 256; off <<= 1) {
    int pc = 0;
    if (t >= off) pc = sC[t - off];
    __syncthreads();
    tot += pc;
    sC[t] = tot;
    __syncthreads();
  }
  const int base = tot - nst;
  const int total = sC[255];
  if (t == 0) { ccnt[b] = total; cstart[b * (SS + 1) + total] = SS; }
  ext = extIn; int id = base;
#pragma unroll
  for (int e = 0; e < 16; ++e) {
    int cont = (labv[e] == 1) & ext;
    if (!cont) cstart[b * (SS + 1) + id++] = t * 16 + e;
    ext = (labv[e] == 0) | cont;
  }
}

// ---------------- kernel 4: segment-mean pooling from h16 (1 wave / chunk) --
__global__ __launch_bounds__(256) void k_pool(
    const u16* __restrict__ h16, const int* __restrict__ cstart,
    const int* __restrict__ ccnt, u16* __restrict__ cemb)
{
  const int t = threadIdx.x, w = t >> 6, lane = t & 63;
  const int gw = blockIdx.x * 4 + w;
  const int b = gw >> 12, c = gw & (SS - 1);
  u16* out = cemb + (size_t)gw * DD + lane * 16;
  if (c >= ccnt[b]) {
    ushort8 z = {0, 0, 0, 0, 0, 0, 0, 0};
    *(ushort8*)out = z; *(ushort8*)(out + 8) = z;
    return;
  }
  const int s0 = cstart[b * (SS + 1) + c], s1 = cstart[b * (SS + 1) + c + 1];
  float acc[16] = {};
  for (int s = s0; s < s1; ++s) {
    const ushort8* hp = (const ushort8*)(h16 + ((size_t)b * SS + s) * DD + lane * 16);
    ushort8 a = hp[0], bb = hp[1];
#pragma unroll
    for (int e = 0; e < 8; ++e) { acc[e] += bf2f(a[e]); acc[8 + e] += bf2f(bb[e]); }
  }
  const float inv = 1.f / (float)(s1 - s0);
  ushort8 o0, o1;
#pragma unroll
  for (int e = 0; e < 8; ++e) { o0[e] = f2bf(acc[e] * inv); o1[e] = f2bf(acc[8 + e] * inv); }
  *(ushort8*)out = o0; *(ushort8*)(out + 8) = o1;
}

// ---------------- bvWo[n] = sum_j bv[j]*Wo[j,n] ------------------------------
__global__ __launch_bounds__(256) void k_bvwo(
    const float* __restrict__ bv, const float* __restrict__ Wo,
    const float* __restrict__ bo, float* __restrict__ outv)
{
  const int n = blockIdx.x * 256 + threadIdx.x;
  float s = 0.f;
#pragma unroll 8
  for (int j = 0; j < 1024; ++j) s += bv[j] * Wo[(size_t)j * 1024 + n];
  outv[n] = s;
}

// ---------------- Wvo^T = small 1024^3 GEMM: C[n,k]=sum_j WoT[n,j]*Wv[k,j] --
__global__ __launch_bounds__(256) void k_wvo(
    const u16* __restrict__ WoT, const u16* __restrict__ Wvn, u16* __restrict__ WvoT)
{
  __shared__ u16 lA[64 * 64], lB[64 * 64];
  const int t = threadIdx.x, lane = t & 63, w = t >> 6;
  const int m0 = blockIdx.y * 64, n0 = blockIdx.x * 64;
  const int trow = t >> 3;
  const int schunk = ((t & 7) ^ (trow & 7)) * 8;
  const u16* Ag = WoT + (size_t)(m0 + trow) * 1024 + schunk;
  const u16* Bg = Wvn + (size_t)(n0 + trow) * 1024 + schunk;
  u16* dA = lA + t * 8;
  u16* dB = lB + t * 8;
  f32x4 acc[4];
#pragma unroll
  for (int i = 0; i < 4; ++i) acc[i] = (f32x4){0.f, 0.f, 0.f, 0.f};
  const int lrow = lane & 15, hi = lane >> 4;
  const int co0 = (hi ^ (lrow & 7)) * 8;
  const int co1 = ((4 + hi) ^ (lrow & 7)) * 8;
  for (int kt = 0; kt < 1024; kt += 64) {
    gload16(Ag + kt, dA); gload16(Ag + (size_t)32 * 1024 + kt, dA + 2048);
    gload16(Bg + kt, dB); gload16(Bg + (size_t)32 * 1024 + kt, dB + 2048);
    __syncthreads();
#pragma unroll
    for (int ks = 0; ks < 2; ++ks) {
      const int co = ks ? co1 : co0;
      short8 af = *(const short8*)(lA + (w * 16 + lrow) * 64 + co);
#pragma unroll
      for (int ni = 0; ni < 4; ++ni) {
        short8 bf8 = *(const short8*)(lB + (ni * 16 + lrow) * 64 + co);
        acc[ni] = __builtin_amdgcn_mfma_f32_16x16x32_bf16(af, bf8, acc[ni], 0, 0, 0);
      }
    }
    __syncthreads();
  }
#pragma unroll
  for (int ni = 0; ni < 4; ++ni)
#pragma unroll
    for (int q = 0; q < 4; ++q)
      WvoT[(size_t)(m0 + w * 16 + hi * 4 + q) * 1024 + n0 + ni * 16 + lrow] = f2bf(acc[ni][q]);
}

// ---------------- 256x256 NT bf16 GEMM, BK=64, 8 waves, 4-phase (r5 schedule)
// The best-measured schedule (r5: 535 us total). Gray-code quadrants
// (0,0),(0,1),(1,0),(1,1), 16 MFMA/phase, 2 barriers/phase. Staging halves:
//   ph1: SA1(j+1)->buf^1 [last read iter j-1 ph3]   ph2: SA0(j+2)->buf
//   ph3: SB0(j+2)->buf                              ph4: SB1(j+2)->buf
// vmcnt(6) gate in ph4 (3 half-tiles in flight); vmcnt(0) at j==NT-2.
// Added vs r5: CLAMPK/SKIPN/CLAMPM guards (clamp-safe for NT=1,2: gate logic
// degenerates to prologue vmcnt(0) / single vmcnt(0) exactly as unclamped).
template <int OUTF32, int CLAMPK, int SKIPN, int CLAMPM>
__global__ __launch_bounds__(512, 2) void gemm256(
    const u16* __restrict__ A0p, const u16* __restrict__ A1p,
    const u16* __restrict__ A2p, const u16* __restrict__ A3p,
    const u16* __restrict__ Bt, long strideB,
    void* __restrict__ C0, void* __restrict__ C1,
    void* __restrict__ C2, void* __restrict__ C3,
    const float* __restrict__ bias, float scale, int M, int N, int K,
    const int* __restrict__ ccnt)
{
  __shared__ u16 lds[65536];  // 128 KB: A dbuf | B dbuf; C-tile overlay after
  u16* ldsA = lds;
  u16* ldsB = lds + 32768;
  const int t = threadIdx.x, lane = t & 63, w = t >> 6;
  const int wr = w >> 2, wc = w & 3;
  const int z = blockIdx.z;
  const int bid = blockIdx.y * gridDim.x + blockIdx.x;
  const int swz = xcd_swz(bid, gridDim.x * gridDim.y);
  const int m0 = (swz / gridDim.x) * 256, n0 = (swz % gridDim.x) * 256;

  int NT = K >> 6;
  if (SKIPN || CLAMPK) {
    const int cb = ccnt[z];
    const int ntc = (cb + 63) >> 6;
    if (SKIPN && n0 >= (ntc << 6)) return;
    if (CLAMPK && ntc < NT) NT = ntc;
  }
  if (CLAMPM) {
    const int bb = m0 >> 12;
    const int ntc64 = ((ccnt[bb] + 63) >> 6) << 6;
    if ((m0 & 4095) >= ntc64) return;
  }

  const u16* A = (z == 0) ? A0p : (z == 1) ? A1p : (z == 2) ? A2p : A3p;
  void* Cp    = (z == 0) ? C0 : (z == 1) ? C1 : (z == 2) ? C2 : C3;
  const u16* B = Bt + (size_t)z * strideB;

  f32x4 acc[8][4];
#pragma unroll
  for (int i = 0; i < 8; ++i)
#pragma unroll
    for (int j = 0; j < 4; ++j) acc[i][j] = (f32x4){0.f, 0.f, 0.f, 0.f};

  const int trow = t >> 3;
  const u16* Ag = A + (size_t)(m0 + trow) * K + ((t & 7) ^ (trow & 7)) * 8;
  const u16* Bg = B + (size_t)(n0 + trow) * K + ((t & 7) ^ (trow & 7)) * 8;
  u16* dA = ldsA + t * 8;
  u16* dB = ldsB + t * 8;

#define STG_A0(BUF, KT) { gload16(Ag + (size_t)(KT),            dA + (BUF) * 16384 + 0 * 4096); \
                          gload16(Ag + (size_t)128 * K + (KT),  dA + (BUF) * 16384 + 2 * 4096); }
#define STG_A1(BUF, KT) { gload16(Ag + (size_t)64 * K + (KT),   dA + (BUF) * 16384 + 1 * 4096); \
                          gload16(Ag + (size_t)192 * K + (KT),  dA + (BUF) * 16384 + 3 * 4096); }
#define STG_B0(BUF, KT) { gload16(Bg + (size_t)(KT),            dB + (BUF) * 16384 + 0 * 4096); \
                          gload16(Bg + (size_t)64 * K + (KT),   dB + (BUF) * 16384 + 1 * 4096); }
#define STG_B1(BUF, KT) { gload16(Bg + (size_t)128 * K + (KT),  dB + (BUF) * 16384 + 2 * 4096); \
                          gload16(Bg + (size_t)192 * K + (KT),  dB + (BUF) * 16384 + 3 * 4096); }
#define MFMA16(MH, NH, BF) \
  { _Pragma("unroll") for (int ks = 0; ks < 2; ++ks) \
    _Pragma("unroll") for (int mi = 0; mi < 4; ++mi) \
      _Pragma("unroll") for (int ni = 0; ni < 2; ++ni) \
        acc[(MH) * 4 + mi][(NH) * 2 + ni] = __builtin_amdgcn_mfma_f32_16x16x32_bf16( \
            af[mi][ks], BF[ni][ks], acc[(MH) * 4 + mi][(NH) * 2 + ni], 0, 0, 0); }

  const int lrow = lane & 15, hi = lane >> 4;
  const int co0 = (hi ^ (lrow & 7)) * 8;
  const int co1 = ((4 + hi) ^ (lrow & 7)) * 8;

  // prologue: tile0 {A0,B0,B1,A1}, tile1 {A0,B0,B1}; SA1(1) comes at iter0 ph1
  STG_A0(0, 0); STG_B0(0, 0); STG_B1(0, 0); STG_A1(0, 0);
  if (NT > 1) { STG_A0(1, 64); STG_B0(1, 64); STG_B1(1, 64); }
  if (NT > 1) asm volatile("s_waitcnt vmcnt(6)" ::: "memory");  // tile0 landed
  else        asm volatile("s_waitcnt vmcnt(0)" ::: "memory");
  __builtin_amdgcn_s_barrier();
  CFENCE;

  for (int j = 0; j < NT; ++j) {
    const int cur = j & 1;
    const u16* bA = ldsA + cur * 16384;
    const u16* bB = ldsB + cur * 16384;
    const int kt1 = (j + 1) << 6, kt2 = (j + 2) << 6;
    short8 af[4][2], b0[2][2], b1[2][2];
    // ---- ph1 (mh0,nh0): read A-mh0 (8) + B-nh0 (4); stage SA1(j+1)
#pragma unroll
    for (int mi = 0; mi < 4; ++mi) {
      af[mi][0] = *(const short8*)(bA + (wr * 128 + mi * 16 + lrow) * 64 + co0);
      af[mi][1] = *(const short8*)(bA + (wr * 128 + mi * 16 + lrow) * 64 + co1);
    }
#pragma unroll
    for (int ni = 0; ni < 2; ++ni) {
      b0[ni][0] = *(const short8*)(bB + (wc * 32 + ni * 16 + lrow) * 64 + co0);
      b0[ni][1] = *(const short8*)(bB + (wc * 32 + ni * 16 + lrow) * 64 + co1);
    }
    if (j + 1 < NT) STG_A1(cur ^ 1, kt1);
    CFENCE;
    __builtin_amdgcn_s_barrier();
    __builtin_amdgcn_s_setprio(1);
    MFMA16(0, 0, b0);
    __builtin_amdgcn_s_setprio(0);
    __builtin_amdgcn_sched_barrier(0);
    __builtin_amdgcn_s_barrier();
    CFENCE;
    // ---- ph2 (mh0,nh1): read B-nh1 (4); stage SA0(j+2)
#pragma unroll
    for (int ni = 0; ni < 2; ++ni) {
      b1[ni][0] = *(const short8*)(bB + (128 + wc * 32 + ni * 16 + lrow) * 64 + co0);
      b1[ni][1] = *(const short8*)(bB + (128 + wc * 32 + ni * 16 + lrow) * 64 + co1);
    }
    if (j + 2 < NT) STG_A0(cur, kt2);
    CFENCE;
    __builtin_amdgcn_s_barrier();
    __builtin_amdgcn_s_setprio(1);
    MFMA16(0, 1, b1);
    __builtin_amdgcn_s_setprio(0);
    __builtin_amdgcn_sched_barrier(0);
    __builtin_amdgcn_s_barrier();
    CFENCE;
    // ---- ph3 (mh1,nh0): read A-mh1 (8); stage SB0(j+2); b0 from regs
#pragma unroll
    for (int mi = 0; mi < 4; ++mi) {
      af[mi][0] = *(const short8*)(bA + (wr * 128 + 64 + mi * 16 + lrow) * 64 + co0);
      af[mi][1] = *(const short8*)(bA + (wr * 128 + 64 + mi * 16 + lrow) * 64 + co1);
    }
    if (j + 2 < NT) STG_B0(cur, kt2);
    CFENCE;
    __builtin_amdgcn_s_barrier();
    __builtin_amdgcn_s_setprio(1);
    MFMA16(1, 0, b0);
    __builtin_amdgcn_s_setprio(0);
    __builtin_amdgcn_sched_barrier(0);
    __builtin_amdgcn_s_barrier();
    CFENCE;
    // ---- ph4 (mh1,nh1): no reads; stage SB1(j+2); gate before close barrier
    if (j + 2 < NT) STG_B1(cur, kt2);
    CFENCE;
    __builtin_amdgcn_s_barrier();
    __builtin_amdgcn_s_setprio(1);
    MFMA16(1, 1, b1);
    __builtin_amdgcn_s_setprio(0);
    if (j < NT - 2)       asm volatile("s_waitcnt vmcnt(6)" ::: "memory");
    else if (j == NT - 2) asm volatile("s_waitcnt vmcnt(0)" ::: "memory");
    __builtin_amdgcn_sched_barrier(0);
    __builtin_amdgcn_s_barrier();
    CFENCE;
  }

  // epilogue. frag (m,n): row_local = wr*128 + m*16 + (lane>>4)*4 + q,
  // col_local = (n>>1)*128 + wc*32 + (n&1)*16 + (lane&15)
  if (OUTF32) {
    const int rowb = m0 + wr * 128 + (lane >> 4) * 4;
#pragma unroll
    for (int n = 0; n < 4; ++n) {
      const int col = n0 + (n >> 1) * 128 + wc * 32 + (n & 1) * 16 + (lane & 15);
      const float bv = bias ? bias[col] : 0.f;
#pragma unroll
      for (int m = 0; m < 8; ++m)
#pragma unroll
        for (int q = 0; q < 4; ++q)
          ((float*)Cp)[(size_t)(rowb + m * 16 + q) * N + col] = acc[m][n][q] * scale + bv;
    }
  } else {
    // stage C tile in LDS with row-XOR col swizzle, then coalesced copy-out
    __syncthreads();
    u16* cls = lds;
    const int rowl = wr * 128 + (lane >> 4) * 4;
#pragma unroll
    for (int n = 0; n < 4; ++n) {
      const int coll = (n >> 1) * 128 + wc * 32 + (n & 1) * 16 + (lane & 15);
      const float bv = bias ? bias[n0 + coll] : 0.f;
#pragma unroll
      for (int m = 0; m < 8; ++m)
#pragma unroll
        for (int q = 0; q < 4; ++q) {
          const int row = rowl + m * 16 + q;
          cls[row * 256 + (coll ^ (((row >> 2) & 3) << 4))] = f2bf(acc[m][n][q] * scale + bv);
        }
    }
    __syncthreads();
    u16* Cu = (u16*)Cp;
#pragma unroll
    for (int ps = 0; ps < 16; ++ps) {
      const int f = ps * 512 + t;
      const int row = f >> 5, col8 = (f & 31);
      const int scol8 = col8 ^ (((row >> 2) & 3) << 1);
      *(ushort8*)(Cu + (size_t)(m0 + row) * N + n0 + col8 * 8) =
          *(const ushort8*)(cls + row * 256 + scol8 * 8);
    }
  }
#undef STG_A0
#undef STG_A1
#undef STG_B0
#undef STG_B1
#undef MFMA16
}

// ---------------- masked row softmax, bf16 in-place, z-folded, col-clamped --
__global__ __launch_bounds__(256) void k_softmax(
    u16* __restrict__ s0, u16* __restrict__ s1, u16* __restrict__ s2,
    u16* __restrict__ s3, const int* __restrict__ ccnt)
{
  const int t = threadIdx.x, lane = t & 63, w = t >> 6;
  const int row = blockIdx.x, b = blockIdx.y;
  u16* sc = ((b == 0) ? s0 : (b == 1) ? s1 : (b == 2) ? s2 : s3) + (size_t)row * SS;
  const int Cb = ccnt[b];
  const int ntc64 = ((Cb + 63) >> 6) << 6;   // cols >= ntc64 never read by PV
  const int cb0 = t * 16;
  const int active = cb0 < ntc64;
  u16* p = sc + cb0;
  ushort8 v0 = {0, 0, 0, 0, 0, 0, 0, 0}, v1 = {0, 0, 0, 0, 0, 0, 0, 0};
  if (active) { v0 = *(ushort8*)p; v1 = *(ushort8*)(p + 8); }
  float x[16];
#pragma unroll
  for (int e = 0; e < 8; ++e) { x[e] = bf2f(v0[e]); x[8 + e] = bf2f(v1[e]); }
  float m = -1e30f;
#pragma unroll
  for (int e = 0; e < 16; ++e) if (cb0 + e < Cb) m = fmaxf(m, x[e]);
#pragma unroll
  for (int off = 32; off; off >>= 1) m = fmaxf(m, __shfl_xor(m, off));
  __shared__ float red[4], red2[4];
  if (lane == 0) red[w] = m;
  __syncthreads();
  m = fmaxf(fmaxf(red[0], red[1]), fmaxf(red[2], red[3]));
  float ssum = 0.f;
#pragma unroll
  for (int e = 0; e < 16; ++e) {
    float ev = (cb0 + e < Cb) ? __expf(x[e] - m) : 0.f;
    x[e] = ev; ssum += ev;
  }
#pragma unroll
  for (int off = 32; off; off >>= 1) ssum += __shfl_xor(ssum, off);
  if (lane == 0) red2[w] = ssum;
  __syncthreads();
  ssum = red2[0] + red2[1] + red2[2] + red2[3];
  const float inv = 1.f / ssum;
  if (active) {
#pragma unroll
    for (int e = 0; e < 8; ++e) { v0[e] = f2bf(x[e] * inv); v1[e] = f2bf(x[8 + e] * inv); }
    *(ushort8*)p = v0; *(ushort8*)(p + 8) = v1;
  }
}

// ---------------- bf16 transpose v[b][c][d] -> vT[b][d][c], c-clamped -------
__global__ __launch_bounds__(256) void k_transpose(
    const u16* __restrict__ v, u16* __restrict__ vt, const int* __restrict__ ccnt)
{
  const int b = blockIdx.z;
  const int c0 = blockIdx.y * 64;
  if (c0 >= (((ccnt[b] + 63) >> 6) << 6)) return;  // vt cols never read by PV
  __shared__ u16 ts[64][80];
  const int t = threadIdx.x;
  const int d0 = blockIdx.x * 64;
#pragma unroll
  for (int p = 0; p < 2; ++p) {
    const int idx = p * 256 + t, r = idx >> 3, cc = idx & 7;
    ushort8 val = *(const ushort8*)(v + ((size_t)b * SS + c0 + r) * DD + d0 + cc * 8);
    *(ushort8*)&ts[r][(cc ^ ((r >> 3) & 7)) * 8] = val;
  }
  __syncthreads();
#pragma unroll
  for (int p = 0; p < 2; ++p) {
    const int idx = p * 256 + t, r = idx >> 3, cc = idx & 7;
    ushort8 o;
#pragma unroll
    for (int e = 0; e < 8; ++e)
      o[e] = ts[cc * 8 + e][(((r >> 3) ^ cc) << 3) + (r & 7)];
    *(ushort8*)(vt + ((size_t)b * DD + d0 + r) * SS + c0 + cc * 8) = o;
  }
}

// ---------------- loss finalize ---------------------------------------------
__global__ __launch_bounds__(256) void k_lossfin(
    const float* __restrict__ part, float* __restrict__ out)
{
  const int t = threadIdx.x, lane = t & 63, w = t >> 6;
  float s = 0.f;
  for (int i = t; i < 4096; i += 256) s += part[i];
#pragma unroll
  for (int off = 32; off; off >>= 1) s += __shfl_xor(s, off);
  __shared__ float r[4];
  if (lane == 0) r[w] = s;
  __syncthreads();
  if (t == 0) out[0] = (r[0] + r[1] + r[2] + r[3]) * (1.f / (NB * SS));
}

extern "C" void kernel_launch(void* const* d_in, const int* in_sizes, int n_in,
                              void* d_out, int out_size, void* d_ws, size_t ws_size,
                              hipStream_t stream) {
  const float* h  = (const float*)d_in[0];
  const int* plab = (const int*)d_in[1];
  const float* Wl = (const float*)d_in[2];
  const float* bl = (const float*)d_in[3];
  const float* Wq = (const float*)d_in[4];
  const float* bq = (const float*)d_in[5];
  const float* Wk = (const float*)d_in[6];
  const float* bk = (const float*)d_in[7];
  const float* Wv = (const float*)d_in[8];
  const float* bv = (const float*)d_in[9];
  const float* Wo = (const float*)d_in[10];
  const float* bo = (const float*)d_in[11];
  float* out = (float*)d_out;

  char* ws = (char*)d_ws;
  const size_t SZ = (size_t)NB * SS * DD * 2;  // 32 MB
  const size_t SD = (size_t)SS * DD;           // per-batch elems
  u16* h16      = (u16*)(ws + 0 * SZ);  // dead after q-GEMM -> s0
  u16* cemb     = (u16*)(ws + 1 * SZ);  // dead after k/v2-GEMM -> s1
  u16* q        = (u16*)(ws + 2 * SZ);
  u16* kk       = (u16*)(ws + 3 * SZ);
  u16* vv       = (u16*)(ws + 4 * SZ);  // dead after transpose -> s2
  u16* vt       = (u16*)(ws + 5 * SZ);
  u16* Wt       = (u16*)(ws + 6 * SZ);  // 8 MB: Wq^T | Wk^T | Wv | Wo^T; slot0 -> Wvo^T
  char* ws2     = ws + 6 * SZ + (size_t)4 * 1024 * 1024 * 2;
  int* pred     = (int*)ws2;
  int* cstart   = (int*)(ws2 + 65536);
  int* ccnt     = (int*)(ws2 + 65536 + 4 * (SS + 1) * 4);
  float* lossPart = (float*)(ws2 + 65536 + 4 * (SS + 1) * 4 + 64);
  float* bvwo   = (float*)(ws2 + 65536 + 4 * (SS + 1) * 4 + 64 + 16384);
  // s3: fresh 32 MB at the end of ws (total footprint ~233 MB)
  u16* s3 = (u16*)(ws + 6 * SZ + (size_t)9 * 1024 * 1024);
  u16* s0 = h16;
  u16* s1 = cemb;
  u16* s2 = vv;

  k_logits<<<dim3(NB * SS / 4), 256, 0, stream>>>(h, plab, Wl, bl, h16, pred, lossPart);
  k_wconv<<<dim3(4 * 1024 * 1024 / 256), 256, 0, stream>>>(Wq, Wk, Wv, Wo, Wt);
  k_scan<<<dim3(NB), 256, 0, stream>>>(pred, cstart, ccnt);
  k_pool<<<dim3(NB * SS / 4), 256, 0, stream>>>(h16, cstart, ccnt, cemb);
  k_bvwo<<<dim3(4), 256, 0, stream>>>(bv, Wo, bo, bvwo);

  // q = h16 @ Wq + bq
  gemm256<0, 0, 0, 0><<<dim3(DD / 256, NB * SS / 256, 1), 512, 0, stream>>>(
      h16, h16, h16, h16, Wt, 0, q, q, q, q,
      bq, 1.f, NB * SS, DD, DD, nullptr);
  // Wvo^T = (Wv@Wo)^T into Wt slot0 (Wq^T dead)
  k_wvo<<<dim3(16, 16), 256, 0, stream>>>(Wt + 3 * (1 << 20), Wt + 2 * (1 << 20), Wt);
  // k = cemb @ Wk + bk  (rows >= ntc64 skipped)
  gemm256<0, 0, 0, 1><<<dim3(DD / 256, NB * SS / 256, 1), 512, 0, stream>>>(
      cemb, cemb, cemb, cemb, Wt + (1 << 20), 0, kk, kk, kk, kk,
      bk, 1.f, NB * SS, DD, DD, ccnt);
  // v2 = cemb @ Wvo + bvWo  (rows >= ntc64 skipped)
  gemm256<0, 0, 0, 1><<<dim3(DD / 256, NB * SS / 256, 1), 512, 0, stream>>>(
      cemb, cemb, cemb, cemb, Wt, 0, vv, vv, vv, vv,
      bvwo, 1.f, NB * SS, DD, DD, ccnt);
  k_transpose<<<dim3(DD / 64, SS / 64, NB), 256, 0, stream>>>(vv, vt, ccnt);

  const float scl = 1.f / 32.f;  // 1/sqrt(DC)
  // scores: all 4 batches, one dispatch (skip masked n-blocks)
  gemm256<0, 0, 1, 0><<<dim3(SS / 256, SS / 256, NB), 512, 0, stream>>>(
      q, q + SD, q + 2 * SD, q + 3 * SD, kk, (long)SD,
      s0, s1, s2, s3, nullptr, scl, SS, SS, DD, ccnt);
  k_softmax<<<dim3(SS, NB), 256, 0, stream>>>(s0, s1, s2, s3, ccnt);
  // ch_out = attn @ v2 + bo  (K clamped to ceil(ccnt/64))
  gemm256<1, 1, 0, 0><<<dim3(DD / 256, SS / 256, NB), 512, 0, stream>>>(
      s0, s1, s2, s3, vt, (long)SD,
      out, out + SD, out + 2 * SD, out + 3 * SD,
      bo, 1.f, SS, DD, SS, ccnt);
  k_lossfin<<<dim3(1), 256, 0, stream>>>(lossPart, out + (size_t)NB * SS * DD);
}

// Round 13
// 536.186 us; speedup vs baseline: 6.7776x; 1.0069x over previous
//
#include <hip/hip_runtime.h>

typedef unsigned short u16;
typedef __attribute__((ext_vector_type(8))) short short8;
typedef __attribute__((ext_vector_type(8))) unsigned short ushort8;
typedef __attribute__((ext_vector_type(4))) unsigned short ushort4v;
typedef __attribute__((ext_vector_type(4))) float f32x4;

#define NB 4
#define SS 4096
#define DD 1024
#define CFENCE asm volatile("" ::: "memory")

__device__ __forceinline__ u16 f2bf(float x) {
  unsigned u = __builtin_bit_cast(unsigned, x);
  u = (u + 0x7FFFu + ((u >> 16) & 1u)) >> 16;
  return (u16)u;
}
__device__ __forceinline__ float bf2f(u16 b) {
  unsigned u = ((unsigned)b) << 16;
  return __builtin_bit_cast(float, u);
}
__device__ __forceinline__ void gload16(const void* g, void* l) {
  __builtin_amdgcn_global_load_lds((const __attribute__((address_space(1))) void*)g,
                                   (__attribute__((address_space(3))) void*)l, 16, 0, 0);
}
// bijective XCD-aware swizzle (m204)
__device__ __forceinline__ int xcd_swz(int bid, int nwg) {
  const int x = bid & 7, idx = bid >> 3;
  const int q = nwg >> 3, r = nwg & 7;
  return (x < r ? x * (q + 1) : r * (q + 1) + (x - r) * q) + idx;
}

// ---------------- kernel 1: logits (f32), loss partials, pred, h->bf16 -----
__global__ __launch_bounds__(256) void k_logits(
    const float* __restrict__ h, const int* __restrict__ lab,
    const float* __restrict__ Wl, const float* __restrict__ bl,
    u16* __restrict__ h16, int* __restrict__ pred, float* __restrict__ lossPart)
{
  const int t = threadIdx.x, w = t >> 6, lane = t & 63;
  const int tok = blockIdx.x * 4 + w;
  const float4* h4p = (const float4*)(h + (size_t)tok * DD);
  const float4* wl4 = (const float4*)Wl;
  float p0 = 0.f, p1 = 0.f, p2 = 0.f, p3 = 0.f;
#pragma unroll
  for (int i = 0; i < 4; ++i) {
    const int d = i * 256 + lane * 4;
    float4 hv = h4p[i * 64 + lane];
    ushort4v hb;
    hb[0] = f2bf(hv.x); hb[1] = f2bf(hv.y); hb[2] = f2bf(hv.z); hb[3] = f2bf(hv.w);
    *(ushort4v*)(h16 + (size_t)tok * DD + d) = hb;
    float4 w0 = wl4[d], w1 = wl4[d + 1], w2 = wl4[d + 2], w3 = wl4[d + 3];
    p0 += hv.x * w0.x + hv.y * w1.x + hv.z * w2.x + hv.w * w3.x;
    p1 += hv.x * w0.y + hv.y * w1.y + hv.z * w2.y + hv.w * w3.y;
    p2 += hv.x * w0.z + hv.y * w1.z + hv.z * w2.z + hv.w * w3.z;
    p3 += hv.x * w0.w + hv.y * w1.w + hv.z * w2.w + hv.w * w3.w;
  }
#pragma unroll
  for (int m = 32; m; m >>= 1) {
    p0 += __shfl_xor(p0, m); p1 += __shfl_xor(p1, m);
    p2 += __shfl_xor(p2, m); p3 += __shfl_xor(p3, m);
  }
  __shared__ float ls[4];
  if (lane == 0) {
    float l[4] = {p0 + bl[0], p1 + bl[1], p2 + bl[2], p3 + bl[3]};
    int bi = 0; float bv = l[0];
#pragma unroll
    for (int c = 1; c < 4; ++c) if (l[c] > bv) { bv = l[c]; bi = c; }
    pred[tok] = bi;
    float se = 0.f;
#pragma unroll
    for (int c = 0; c < 4; ++c) se += expf(l[c] - bv);
    float lse = bv + logf(se);
    ls[w] = lse - l[lab[tok]];
  }
  __syncthreads();
  if (t == 0) lossPart[blockIdx.x] = ls[0] + ls[1] + ls[2] + ls[3];
}

// ---------------- kernel 2: weights -> bf16. slots: 0=Wq^T 1=Wk^T 2=Wv(plain) 3=Wo^T
__global__ __launch_bounds__(256) void k_wconv(
    const float* __restrict__ W0, const float* __restrict__ W1,
    const float* __restrict__ W2, const float* __restrict__ W3,
    u16* __restrict__ Wt)
{
  const int gid = blockIdx.x * 256 + threadIdx.x;
  const int mat = gid >> 20;
  const int rem = gid & ((1 << 20) - 1);
  const int n = rem >> 10, k = rem & 1023;
  const float* W = (mat == 0) ? W0 : (mat == 1) ? W1 : (mat == 2) ? W2 : W3;
  const float v = (mat == 2) ? W[(size_t)n * 1024 + k] : W[(size_t)k * 1024 + n];
  Wt[(size_t)gid] = f2bf(v);
}

// ---------------- kernel 3: BIOS chunk scan (1 block / batch) --------------
__global__ __launch_bounds__(256) void k_scan(
    const int* __restrict__ pred, int* __restrict__ cstart, int* __restrict__ ccnt)
{
  const int b = blockIdx.x, t = threadIdx.x;
  const int4* p4 = (const int4*)(pred + (size_t)b * SS);
  int labv[16];
#pragma unroll
  for (int i = 0; i < 4; ++i) {
    int4 v = p4[t * 4 + i];
    labv[i * 4 + 0] = v.x; labv[i * 4 + 1] = v.y;
    labv[i * 4 + 2] = v.z; labv[i * 4 + 3] = v.w;
  }
  int A = 0, Bc = 1;
#pragma unroll
  for (int e = 0; e < 16; ++e) {
    int a = (labv[e] == 0), bb = (labv[e] == 1);
    A = a | (bb & A);
    Bc = bb & Bc;
  }
  __shared__ int sA[256], sB[256], sC[256];
  sA[t] = A; sB[t] = Bc;
  __syncthreads();
  for (int off = 1; off < 256; off <<= 1) {
    int pa = 0, pb = 1;
    if (t >= off) { pa = sA[t - off]; pb = sB[t - off]; }
    __syncthreads();
    A = A | (Bc & pa); Bc = Bc & pb;
    sA[t] = A; sB[t] = Bc;
    __syncthreads();
  }
  const int extIn = (t == 0) ? 0 : sA[t - 1];
  int ext = extIn, nst = 0;
#pragma unroll
  for (int e = 0; e < 16; ++e) {
    int cont = (labv[e] == 1) & ext;
    nst += !cont;
    ext = (labv[e] == 0) | cont;
  }
  sC[t] = nst;
  __syncthreads();
  int tot = nst;
  for (int off = 1; off < 256; off <<= 1) {
    int pc = 0;
    if (t >= off) pc = sC[t - off];
    __syncthreads();
    tot += pc;
    sC[t] = tot;
    __syncthreads();
  }
  const int base = tot - nst;
  const int total = sC[255];
  if (t == 0) { ccnt[b] = total; cstart[b * (SS + 1) + total] = SS; }
  ext = extIn; int id = base;
#pragma unroll
  for (int e = 0; e < 16; ++e) {
    int cont = (labv[e] == 1) & ext;
    if (!cont) cstart[b * (SS + 1) + id++] = t * 16 + e;
    ext = (labv[e] == 0) | cont;
  }
}

// ---------------- kernel 4: segment-mean pooling from h16 (1 wave / chunk) --
__global__ __launch_bounds__(256) void k_pool(
    const u16* __restrict__ h16, const int* __restrict__ cstart,
    const int* __restrict__ ccnt, u16* __restrict__ cemb)
{
  const int t = threadIdx.x, w = t >> 6, lane = t & 63;
  const int gw = blockIdx.x * 4 + w;
  const int b = gw >> 12, c = gw & (SS - 1);
  u16* out = cemb + (size_t)gw * DD + lane * 16;
  if (c >= ccnt[b]) {
    ushort8 z = {0, 0, 0, 0, 0, 0, 0, 0};
    *(ushort8*)out = z; *(ushort8*)(out + 8) = z;
    return;
  }
  const int s0 = cstart[b * (SS + 1) + c], s1 = cstart[b * (SS + 1) + c + 1];
  float acc[16] = {};
  for (int s = s0; s < s1; ++s) {
    const ushort8* hp = (const ushort8*)(h16 + ((size_t)b * SS + s) * DD + lane * 16);
    ushort8 a = hp[0], bb = hp[1];
#pragma unroll
    for (int e = 0; e < 8; ++e) { acc[e] += bf2f(a[e]); acc[8 + e] += bf2f(bb[e]); }
  }
  const float inv = 1.f / (float)(s1 - s0);
  ushort8 o0, o1;
#pragma unroll
  for (int e = 0; e < 8; ++e) { o0[e] = f2bf(acc[e] * inv); o1[e] = f2bf(acc[8 + e] * inv); }
  *(ushort8*)out = o0; *(ushort8*)(out + 8) = o1;
}

// ---------------- biasKV: [0:1024) = bv@Wo (v2 bias), [1024:2048) = bk ------
__global__ __launch_bounds__(256) void k_biaskv(
    const float* __restrict__ bv, const float* __restrict__ Wo,
    const float* __restrict__ bk, float* __restrict__ outv)
{
  const int n = blockIdx.x * 256 + threadIdx.x;
  float s = 0.f;
#pragma unroll 8
  for (int j = 0; j < 1024; ++j) s += bv[j] * Wo[(size_t)j * 1024 + n];
  outv[n] = s;
  outv[1024 + n] = bk[n];
}

// ---------------- Wvo^T = small 1024^3 GEMM: C[n,k]=sum_j WoT[n,j]*Wv[k,j] --
__global__ __launch_bounds__(256) void k_wvo(
    const u16* __restrict__ WoT, const u16* __restrict__ Wvn, u16* __restrict__ WvoT)
{
  __shared__ u16 lA[64 * 64], lB[64 * 64];
  const int t = threadIdx.x, lane = t & 63, w = t >> 6;
  const int m0 = blockIdx.y * 64, n0 = blockIdx.x * 64;
  const int trow = t >> 3;
  const int schunk = ((t & 7) ^ (trow & 7)) * 8;
  const u16* Ag = WoT + (size_t)(m0 + trow) * 1024 + schunk;
  const u16* Bg = Wvn + (size_t)(n0 + trow) * 1024 + schunk;
  u16* dA = lA + t * 8;
  u16* dB = lB + t * 8;
  f32x4 acc[4];
#pragma unroll
  for (int i = 0; i < 4; ++i) acc[i] = (f32x4){0.f, 0.f, 0.f, 0.f};
  const int lrow = lane & 15, hi = lane >> 4;
  const int co0 = (hi ^ (lrow & 7)) * 8;
  const int co1 = ((4 + hi) ^ (lrow & 7)) * 8;
  for (int kt = 0; kt < 1024; kt += 64) {
    gload16(Ag + kt, dA); gload16(Ag + (size_t)32 * 1024 + kt, dA + 2048);
    gload16(Bg + kt, dB); gload16(Bg + (size_t)32 * 1024 + kt, dB + 2048);
    __syncthreads();
#pragma unroll
    for (int ks = 0; ks < 2; ++ks) {
      const int co = ks ? co1 : co0;
      short8 af = *(const short8*)(lA + (w * 16 + lrow) * 64 + co);
#pragma unroll
      for (int ni = 0; ni < 4; ++ni) {
        short8 bf8 = *(const short8*)(lB + (ni * 16 + lrow) * 64 + co);
        acc[ni] = __builtin_amdgcn_mfma_f32_16x16x32_bf16(af, bf8, acc[ni], 0, 0, 0);
      }
    }
    __syncthreads();
  }
#pragma unroll
  for (int ni = 0; ni < 4; ++ni)
#pragma unroll
    for (int q = 0; q < 4; ++q)
      WvoT[(size_t)(m0 + w * 16 + hi * 4 + q) * 1024 + n0 + ni * 16 + lrow] = f2bf(acc[ni][q]);
}

// ---------------- 256x256 NT bf16 GEMM, BK=64, 8 waves, 4-phase (r5 schedule)
// Gray-code quadrants, 16 MFMA/phase, 2 barriers/phase, staggered staging,
// vmcnt(6) gate in ph4 (vmcnt(0) at j==NT-2).
// SPLITC: logical N=2*ldc with B rows [0,ldc)->C0, [ldc,2*ldc)->C1 (k|v2 fuse).
template <int OUTF32, int CLAMPK, int SKIPN, int CLAMPM, int SPLITC>
__global__ __launch_bounds__(512, 2) void gemm256(
    const u16* __restrict__ A0p, const u16* __restrict__ A1p,
    const u16* __restrict__ A2p, const u16* __restrict__ A3p,
    const u16* __restrict__ Bt, long strideB,
    void* __restrict__ C0, void* __restrict__ C1,
    void* __restrict__ C2, void* __restrict__ C3,
    const float* __restrict__ bias, float scale, int M, int N, int K,
    const int* __restrict__ ccnt)
{
  __shared__ u16 lds[65536];  // 128 KB: A dbuf | B dbuf; C-tile overlay after
  u16* ldsA = lds;
  u16* ldsB = lds + 32768;
  const int t = threadIdx.x, lane = t & 63, w = t >> 6;
  const int wr = w >> 2, wc = w & 3;
  const int z = blockIdx.z;
  const int bid = blockIdx.y * gridDim.x + blockIdx.x;
  const int swz = xcd_swz(bid, gridDim.x * gridDim.y);
  const int m0 = (swz / gridDim.x) * 256, n0 = (swz % gridDim.x) * 256;

  int NT = K >> 6;
  if (SKIPN || CLAMPK) {
    const int cb = ccnt[z];
    const int ntc = (cb + 63) >> 6;
    if (SKIPN && n0 >= (ntc << 6)) return;
    if (CLAMPK && ntc < NT) NT = ntc;
  }
  if (CLAMPM) {
    const int bb = m0 >> 12;
    const int ntc64 = ((ccnt[bb] + 63) >> 6) << 6;
    if ((m0 & 4095) >= ntc64) return;
  }

  const u16* A = (z == 0) ? A0p : (z == 1) ? A1p : (z == 2) ? A2p : A3p;
  void* Cp    = (z == 0) ? C0 : (z == 1) ? C1 : (z == 2) ? C2 : C3;
  const u16* B = Bt + (size_t)z * strideB;

  f32x4 acc[8][4];
#pragma unroll
  for (int i = 0; i < 8; ++i)
#pragma unroll
    for (int j = 0; j < 4; ++j) acc[i][j] = (f32x4){0.f, 0.f, 0.f, 0.f};

  const int trow = t >> 3;
  const u16* Ag = A + (size_t)(m0 + trow) * K + ((t & 7) ^ (trow & 7)) * 8;
  const u16* Bg = B + (size_t)(n0 + trow) * K + ((t & 7) ^ (trow & 7)) * 8;
  u16* dA = ldsA + t * 8;
  u16* dB = ldsB + t * 8;

#define STG_A0(BUF, KT) { gload16(Ag + (size_t)(KT),            dA + (BUF) * 16384 + 0 * 4096); \
                          gload16(Ag + (size_t)128 * K + (KT),  dA + (BUF) * 16384 + 2 * 4096); }
#define STG_A1(BUF, KT) { gload16(Ag + (size_t)64 * K + (KT),   dA + (BUF) * 16384 + 1 * 4096); \
                          gload16(Ag + (size_t)192 * K + (KT),  dA + (BUF) * 16384 + 3 * 4096); }
#define STG_B0(BUF, KT) { gload16(Bg + (size_t)(KT),            dB + (BUF) * 16384 + 0 * 4096); \
                          gload16(Bg + (size_t)64 * K + (KT),   dB + (BUF) * 16384 + 1 * 4096); }
#define STG_B1(BUF, KT) { gload16(Bg + (size_t)128 * K + (KT),  dB + (BUF) * 16384 + 2 * 4096); \
                          gload16(Bg + (size_t)192 * K + (KT),  dB + (BUF) * 16384 + 3 * 4096); }
#define MFMA16(MH, NH, BF) \
  { _Pragma("unroll") for (int ks = 0; ks < 2; ++ks) \
    _Pragma("unroll") for (int mi = 0; mi < 4; ++mi) \
      _Pragma("unroll") for (int ni = 0; ni < 2; ++ni) \
        acc[(MH) * 4 + mi][(NH) * 2 + ni] = __builtin_amdgcn_mfma_f32_16x16x32_bf16( \
            af[mi][ks], BF[ni][ks], acc[(MH) * 4 + mi][(NH) * 2 + ni], 0, 0, 0); }

  const int lrow = lane & 15, hi = lane >> 4;
  const int co0 = (hi ^ (lrow & 7)) * 8;
  const int co1 = ((4 + hi) ^ (lrow & 7)) * 8;

  // prologue: tile0 {A0,B0,B1,A1}, tile1 {A0,B0,B1}; SA1(1) comes at iter0 ph1
  STG_A0(0, 0); STG_B0(0, 0); STG_B1(0, 0); STG_A1(0, 0);
  if (NT > 1) { STG_A0(1, 64); STG_B0(1, 64); STG_B1(1, 64); }
  if (NT > 1) asm volatile("s_waitcnt vmcnt(6)" ::: "memory");  // tile0 landed
  else        asm volatile("s_waitcnt vmcnt(0)" ::: "memory");
  __builtin_amdgcn_s_barrier();
  CFENCE;

  for (int j = 0; j < NT; ++j) {
    const int cur = j & 1;
    const u16* bA = ldsA + cur * 16384;
    const u16* bB = ldsB + cur * 16384;
    const int kt1 = (j + 1) << 6, kt2 = (j + 2) << 6;
    short8 af[4][2], b0[2][2], b1[2][2];
    // ---- ph1 (mh0,nh0): read A-mh0 (8) + B-nh0 (4); stage SA1(j+1)
#pragma unroll
    for (int mi = 0; mi < 4; ++mi) {
      af[mi][0] = *(const short8*)(bA + (wr * 128 + mi * 16 + lrow) * 64 + co0);
      af[mi][1] = *(const short8*)(bA + (wr * 128 + mi * 16 + lrow) * 64 + co1);
    }
#pragma unroll
    for (int ni = 0; ni < 2; ++ni) {
      b0[ni][0] = *(const short8*)(bB + (wc * 32 + ni * 16 + lrow) * 64 + co0);
      b0[ni][1] = *(const short8*)(bB + (wc * 32 + ni * 16 + lrow) * 64 + co1);
    }
    if (j + 1 < NT) STG_A1(cur ^ 1, kt1);
    CFENCE;
    __builtin_amdgcn_s_barrier();
    __builtin_amdgcn_s_setprio(1);
    MFMA16(0, 0, b0);
    __builtin_amdgcn_s_setprio(0);
    __builtin_amdgcn_sched_barrier(0);
    __builtin_amdgcn_s_barrier();
    CFENCE;
    // ---- ph2 (mh0,nh1): read B-nh1 (4); stage SA0(j+2)
#pragma unroll
    for (int ni = 0; ni < 2; ++ni) {
      b1[ni][0] = *(const short8*)(bB + (128 + wc * 32 + ni * 16 + lrow) * 64 + co0);
      b1[ni][1] = *(const short8*)(bB + (128 + wc * 32 + ni * 16 + lrow) * 64 + co1);
    }
    if (j + 2 < NT) STG_A0(cur, kt2);
    CFENCE;
    __builtin_amdgcn_s_barrier();
    __builtin_amdgcn_s_setprio(1);
    MFMA16(0, 1, b1);
    __builtin_amdgcn_s_setprio(0);
    __builtin_amdgcn_sched_barrier(0);
    __builtin_amdgcn_s_barrier();
    CFENCE;
    // ---- ph3 (mh1,nh0): read A-mh1 (8); stage SB0(j+2); b0 from regs
#pragma unroll
    for (int mi = 0; mi < 4; ++mi) {
      af[mi][0] = *(const short8*)(bA + (wr * 128 + 64 + mi * 16 + lrow) * 64 + co0);
      af[mi][1] = *(const short8*)(bA + (wr * 128 + 64 + mi * 16 + lrow) * 64 + co1);
    }
    if (j + 2 < NT) STG_B0(cur, kt2);
    CFENCE;
    __builtin_amdgcn_s_barrier();
    __builtin_amdgcn_s_setprio(1);
    MFMA16(1, 0, b0);
    __builtin_amdgcn_s_setprio(0);
    __builtin_amdgcn_sched_barrier(0);
    __builtin_amdgcn_s_barrier();
    CFENCE;
    // ---- ph4 (mh1,nh1): no reads; stage SB1(j+2); gate before close barrier
    if (j + 2 < NT) STG_B1(cur, kt2);
    CFENCE;
    __builtin_amdgcn_s_barrier();
    __builtin_amdgcn_s_setprio(1);
    MFMA16(1, 1, b1);
    __builtin_amdgcn_s_setprio(0);
    if (j < NT - 2)       asm volatile("s_waitcnt vmcnt(6)" ::: "memory");
    else if (j == NT - 2) asm volatile("s_waitcnt vmcnt(0)" ::: "memory");
    __builtin_amdgcn_sched_barrier(0);
    __builtin_amdgcn_s_barrier();
    CFENCE;
  }

  // epilogue. frag (m,n): row_local = wr*128 + m*16 + (lane>>4)*4 + q,
  // col_local = (n>>1)*128 + wc*32 + (n&1)*16 + (lane&15)
  if (OUTF32) {
    const int rowb = m0 + wr * 128 + (lane >> 4) * 4;
#pragma unroll
    for (int n = 0; n < 4; ++n) {
      const int col = n0 + (n >> 1) * 128 + wc * 32 + (n & 1) * 16 + (lane & 15);
      const float bv = bias ? bias[col] : 0.f;
#pragma unroll
      for (int m = 0; m < 8; ++m)
#pragma unroll
        for (int q = 0; q < 4; ++q)
          ((float*)Cp)[(size_t)(rowb + m * 16 + q) * N + col] = acc[m][n][q] * scale + bv;
    }
  } else {
    // stage C tile in LDS with row-XOR col swizzle, then coalesced copy-out
    __syncthreads();
    u16* cls = lds;
    const int rowl = wr * 128 + (lane >> 4) * 4;
#pragma unroll
    for (int n = 0; n < 4; ++n) {
      const int coll = (n >> 1) * 128 + wc * 32 + (n & 1) * 16 + (lane & 15);
      const float bv = bias ? bias[n0 + coll] : 0.f;
#pragma unroll
      for (int m = 0; m < 8; ++m)
#pragma unroll
        for (int q = 0; q < 4; ++q) {
          const int row = rowl + m * 16 + q;
          cls[row * 256 + (coll ^ (((row >> 2) & 3) << 4))] = f2bf(acc[m][n][q] * scale + bv);
        }
    }
    __syncthreads();
    u16* Cu;
    int ncol0, ldc;
    if (SPLITC) {
      const int half = N >> 1;
      ldc = half;
      if (n0 < half) { Cu = (u16*)C0; ncol0 = n0; }
      else           { Cu = (u16*)C1; ncol0 = n0 - half; }
    } else {
      Cu = (u16*)Cp; ncol0 = n0; ldc = N;
    }
#pragma unroll
    for (int ps = 0; ps < 16; ++ps) {
      const int f = ps * 512 + t;
      const int row = f >> 5, col8 = (f & 31);
      const int scol8 = col8 ^ (((row >> 2) & 3) << 1);
      *(ushort8*)(Cu + (size_t)(m0 + row) * ldc + ncol0 + col8 * 8) =
          *(const ushort8*)(cls + row * 256 + scol8 * 8);
    }
  }
#undef STG_A0
#undef STG_A1
#undef STG_B0
#undef STG_B1
#undef MFMA16
}

// ---------------- masked row softmax, bf16 in-place, z-folded, col-clamped --
__global__ __launch_bounds__(256) void k_softmax(
    u16* __restrict__ s0, u16* __restrict__ s1, u16* __restrict__ s2,
    u16* __restrict__ s3, const int* __restrict__ ccnt)
{
  const int t = threadIdx.x, lane = t & 63, w = t >> 6;
  const int row = blockIdx.x, b = blockIdx.y;
  u16* sc = ((b == 0) ? s0 : (b == 1) ? s1 : (b == 2) ? s2 : s3) + (size_t)row * SS;
  const int Cb = ccnt[b];
  const int ntc64 = ((Cb + 63) >> 6) << 6;   // cols >= ntc64 never read by PV
  const int cb0 = t * 16;
  const int active = cb0 < ntc64;
  u16* p = sc + cb0;
  ushort8 v0 = {0, 0, 0, 0, 0, 0, 0, 0}, v1 = {0, 0, 0, 0, 0, 0, 0, 0};
  if (active) { v0 = *(ushort8*)p; v1 = *(ushort8*)(p + 8); }
  float x[16];
#pragma unroll
  for (int e = 0; e < 8; ++e) { x[e] = bf2f(v0[e]); x[8 + e] = bf2f(v1[e]); }
  float m = -1e30f;
#pragma unroll
  for (int e = 0; e < 16; ++e) if (cb0 + e < Cb) m = fmaxf(m, x[e]);
#pragma unroll
  for (int off = 32; off; off >>= 1) m = fmaxf(m, __shfl_xor(m, off));
  __shared__ float red[4], red2[4];
  if (lane == 0) red[w] = m;
  __syncthreads();
  m = fmaxf(fmaxf(red[0], red[1]), fmaxf(red[2], red[3]));
  float ssum = 0.f;
#pragma unroll
  for (int e = 0; e < 16; ++e) {
    float ev = (cb0 + e < Cb) ? __expf(x[e] - m) : 0.f;
    x[e] = ev; ssum += ev;
  }
#pragma unroll
  for (int off = 32; off; off >>= 1) ssum += __shfl_xor(ssum, off);
  if (lane == 0) red2[w] = ssum;
  __syncthreads();
  ssum = red2[0] + red2[1] + red2[2] + red2[3];
  const float inv = 1.f / ssum;
  if (active) {
#pragma unroll
    for (int e = 0; e < 8; ++e) { v0[e] = f2bf(x[e] * inv); v1[e] = f2bf(x[8 + e] * inv); }
    *(ushort8*)p = v0; *(ushort8*)(p + 8) = v1;
  }
}

// ---------------- bf16 transpose v[b][c][d] -> vT[b][d][c], c-clamped -------
__global__ __launch_bounds__(256) void k_transpose(
    const u16* __restrict__ v, u16* __restrict__ vt, const int* __restrict__ ccnt)
{
  const int b = blockIdx.z;
  const int c0 = blockIdx.y * 64;
  if (c0 >= (((ccnt[b] + 63) >> 6) << 6)) return;  // vt cols never read by PV
  __shared__ u16 ts[64][80];
  const int t = threadIdx.x;
  const int d0 = blockIdx.x * 64;
#pragma unroll
  for (int p = 0; p < 2; ++p) {
    const int idx = p * 256 + t, r = idx >> 3, cc = idx & 7;
    ushort8 val = *(const ushort8*)(v + ((size_t)b * SS + c0 + r) * DD + d0 + cc * 8);
    *(ushort8*)&ts[r][(cc ^ ((r >> 3) & 7)) * 8] = val;
  }
  __syncthreads();
#pragma unroll
  for (int p = 0; p < 2; ++p) {
    const int idx = p * 256 + t, r = idx >> 3, cc = idx & 7;
    ushort8 o;
#pragma unroll
    for (int e = 0; e < 8; ++e)
      o[e] = ts[cc * 8 + e][(((r >> 3) ^ cc) << 3) + (r & 7)];
    *(ushort8*)(vt + ((size_t)b * DD + d0 + r) * SS + c0 + cc * 8) = o;
  }
}

// ---------------- loss finalize ---------------------------------------------
__global__ __launch_bounds__(256) void k_lossfin(
    const float* __restrict__ part, float* __restrict__ out)
{
  const int t = threadIdx.x, lane = t & 63, w = t >> 6;
  float s = 0.f;
  for (int i = t; i < 4096; i += 256) s += part[i];
#pragma unroll
  for (int off = 32; off; off >>= 1) s += __shfl_xor(s, off);
  __shared__ float r[4];
  if (lane == 0) r[w] = s;
  __syncthreads();
  if (t == 0) out[0] = (r[0] + r[1] + r[2] + r[3]) * (1.f / (NB * SS));
}

extern "C" void kernel_launch(void* const* d_in, const int* in_sizes, int n_in,
                              void* d_out, int out_size, void* d_ws, size_t ws_size,
                              hipStream_t stream) {
  const float* h  = (const float*)d_in[0];
  const int* plab = (const int*)d_in[1];
  const float* Wl = (const float*)d_in[2];
  const float* bl = (const float*)d_in[3];
  const float* Wq = (const float*)d_in[4];
  const float* bq = (const float*)d_in[5];
  const float* Wk = (const float*)d_in[6];
  const float* bk = (const float*)d_in[7];
  const float* Wv = (const float*)d_in[8];
  const float* bv = (const float*)d_in[9];
  const float* Wo = (const float*)d_in[10];
  const float* bo = (const float*)d_in[11];
  float* out = (float*)d_out;

  char* ws = (char*)d_ws;
  const size_t SZ = (size_t)NB * SS * DD * 2;  // 32 MB
  const size_t SD = (size_t)SS * DD;           // per-batch elems
  u16* h16      = (u16*)(ws + 0 * SZ);  // dead after q-GEMM -> s0
  u16* cemb     = (u16*)(ws + 1 * SZ);  // dead after kv-GEMM -> s1
  u16* q        = (u16*)(ws + 2 * SZ);
  u16* kk       = (u16*)(ws + 3 * SZ);
  u16* vv       = (u16*)(ws + 4 * SZ);  // dead after transpose -> s2
  u16* vt       = (u16*)(ws + 5 * SZ);
  u16* Wt       = (u16*)(ws + 6 * SZ);  // 8 MB: Wq^T | Wk^T | Wv | Wo^T; slot0 -> Wvo^T
  char* ws2     = ws + 6 * SZ + (size_t)4 * 1024 * 1024 * 2;
  int* pred     = (int*)ws2;
  int* cstart   = (int*)(ws2 + 65536);
  int* ccnt     = (int*)(ws2 + 65536 + 4 * (SS + 1) * 4);
  float* lossPart = (float*)(ws2 + 65536 + 4 * (SS + 1) * 4 + 64);
  float* biasKV = (float*)(ws2 + 65536 + 4 * (SS + 1) * 4 + 64 + 16384);  // 2048 f32
  // s3: fresh 32 MB at the end of ws (total footprint ~233 MB)
  u16* s3 = (u16*)(ws + 6 * SZ + (size_t)9 * 1024 * 1024);
  u16* s0 = h16;
  u16* s1 = cemb;
  u16* s2 = vv;

  k_logits<<<dim3(NB * SS / 4), 256, 0, stream>>>(h, plab, Wl, bl, h16, pred, lossPart);
  k_wconv<<<dim3(4 * 1024 * 1024 / 256), 256, 0, stream>>>(Wq, Wk, Wv, Wo, Wt);
  k_scan<<<dim3(NB), 256, 0, stream>>>(pred, cstart, ccnt);
  k_pool<<<dim3(NB * SS / 4), 256, 0, stream>>>(h16, cstart, ccnt, cemb);
  k_biaskv<<<dim3(4), 256, 0, stream>>>(bv, Wo, bk, biasKV);

  // q = h16 @ Wq + bq
  gemm256<0, 0, 0, 0, 0><<<dim3(DD / 256, NB * SS / 256, 1), 512, 0, stream>>>(
      h16, h16, h16, h16, Wt, 0, q, q, q, q,
      bq, 1.f, NB * SS, DD, DD, nullptr);
  // Wvo^T = (Wv@Wo)^T into Wt slot0 (Wq^T dead) -> B for fused kv = [Wvo^T; Wk^T]
  k_wvo<<<dim3(16, 16), 256, 0, stream>>>(Wt + 3 * (1 << 20), Wt + 2 * (1 << 20), Wt);
  // fused kv: C[m, 0:1024) = v2 = cemb@Wvo + bvWo -> vv;
  //           C[m, 1024:2048) = k = cemb@Wk + bk  -> kk.   (rows >= ntc64 skipped)
  gemm256<0, 0, 0, 1, 1><<<dim3(2 * DD / 256, NB * SS / 256, 1), 512, 0, stream>>>(
      cemb, cemb, cemb, cemb, Wt, 0, vv, kk, nullptr, nullptr,
      biasKV, 1.f, NB * SS, 2 * DD, DD, ccnt);
  k_transpose<<<dim3(DD / 64, SS / 64, NB), 256, 0, stream>>>(vv, vt, ccnt);

  const float scl = 1.f / 32.f;  // 1/sqrt(DC)
  // scores: all 4 batches, one dispatch (skip masked n-blocks)
  gemm256<0, 0, 1, 0, 0><<<dim3(SS / 256, SS / 256, NB), 512, 0, stream>>>(
      q, q + SD, q + 2 * SD, q + 3 * SD, kk, (long)SD,
      s0, s1, s2, s3, nullptr, scl, SS, SS, DD, ccnt);
  k_softmax<<<dim3(SS, NB), 256, 0, stream>>>(s0, s1, s2, s3, ccnt);
  // ch_out = attn @ v2 + bo  (K clamped to ceil(ccnt/64))
  gemm256<1, 1, 0, 0, 0><<<dim3(DD / 256, SS / 256, NB), 512, 0, stream>>>(
      s0, s1, s2, s3, vt, (long)SD,
      out, out + SD, out + 2 * SD, out + 3 * SD,
      bo, 1.f, SS, DD, SS, ccnt);
  k_lossfin<<<dim3(1), 256, 0, stream>>>(lossPart, out + (size_t)NB * SS * DD);
}